// Round 8
// baseline (227.347 us; speedup 1.0000x reference)
//
#include <hip/hip_runtime.h>
#include <hip/hip_fp16.h>

#define DM 128
#define NHEADS 8
#define MAXDEG 64
#define SROW 136   // LDS row stride in halves: 128+8 pad (2-way bank alias = free)
#define BSZ (64 * SROW)

typedef _Float16 half8 __attribute__((ext_vector_type(8)));
typedef _Float16 half2v __attribute__((ext_vector_type(2)));
typedef float floatx4 __attribute__((ext_vector_type(4)));

union H8 { half8 v; half2v h2[4]; };

__device__ __forceinline__ half8 cvt_h8(float4 f0, float4 f1) {
  return half8{(_Float16)f0.x, (_Float16)f0.y, (_Float16)f0.z, (_Float16)f0.w,
               (_Float16)f1.x, (_Float16)f1.y, (_Float16)f1.z, (_Float16)f1.w};
}

// ================= fused: CSR-build blocks [0,C) + proj GEMM blocks [C,C+P) =================
// R7 anchor (217us total, proj 66-71) + ONE experiment: double-buffered Bs, one barrier
// per chunk, loads for chunk c+1 issued AFTER the barrier (flying under MFMA+epilogue of
// chunk c) and written to the other buffer after MFMA. This is the correct T14 pattern --
// R2's version issued loads BEFORE the barrier, so the compiler's vmcnt(0) drain at the
// barrier serialized them (that's why R2 regressed). CSR blocks moved to grid FRONT so
// they overlap proj round 1 instead of straggling into a tail round.
// chunk pairs: 0,1->Q  2,3->K(KV lo)  4,5->V(KV hi)  6,7->gate  8->bias cols 512..519
__global__ __launch_bounds__(256) void proj_csr(
    const float* __restrict__ X, const float* __restrict__ Wqkv,
    const float* __restrict__ Wgate, const float* __restrict__ wbias,
    const float* __restrict__ b_gate,
    const int* __restrict__ nsrc, const int* __restrict__ ndst,
    int* __restrict__ cnt, int* __restrict__ csr_dst,
    _Float16* __restrict__ Q, _Float16* __restrict__ KV,
    _Float16* __restrict__ gate, float* __restrict__ bias,
    int M, int E, int C) {
  __shared__ _Float16 As[128 * SROW];
  __shared__ _Float16 Bs[2 * BSZ];
  int tid = threadIdx.x;
  int bid = blockIdx.x;

  if (bid < C) {
    // ---------------- CSR build role (grid front: overlaps proj round 1) ----------------
    int ebase = bid * 8192;
    for (int g = 0; g < 4; g++) {
      int s[8], d[8];
#pragma unroll
      for (int j = 0; j < 8; j++) {
        int e = ebase + (g * 8 + j) * 256 + tid;
        s[j] = (e < E) ? nsrc[e] : -1;
        d[j] = (e < E) ? ndst[e] : 0;
      }
#pragma unroll
      for (int j = 0; j < 8; j++) {
        if (s[j] >= 0) {
          int p = atomicAdd(&cnt[s[j]], 1);
          if (p < MAXDEG) csr_dst[(size_t)s[j] * MAXDEG + p] = d[j];
        }
      }
    }
    return;
  }

  // ---------------- projection GEMM role ----------------
  int pbid = bid - C;
  int m0 = pbid * 128;

  // stage A (fp32 -> fp16): 128 rows x 128 cols
#pragma unroll
  for (int i = 0; i < 4; i++) {
    int u = tid + i * 256;           // 0..1023
    int r = u >> 3;
    int cc = (u & 7) * 16;
    int gr = m0 + r;
    float4 f0, f1, f2, f3;
    if (gr < M) {
      const float4* src = (const float4*)(X + (size_t)gr * 128 + cc);
      f0 = src[0]; f1 = src[1]; f2 = src[2]; f3 = src[3];
    } else {
      f0 = f1 = f2 = f3 = make_float4(0.f, 0.f, 0.f, 0.f);
    }
    *(half8*)(As + r * SROW + cc) = cvt_h8(f0, f1);
    *(half8*)(As + r * SROW + cc + 8) = cvt_h8(f2, f3);
  }

  // stage B chunk 0 into buffer 0 (direct)
#pragma unroll
  for (int i = 0; i < 4; i++) {
    int u = tid + i * 256;           // 0..1023
    int r = u >> 4;                  // 0..63
    int cc = (u & 15) * 8;
    // chunk 0 rows 0..63 are all within Wqkv
    const float* src = Wqkv + (size_t)r * 128 + cc;
    float4 f0 = ((const float4*)src)[0];
    float4 f1 = ((const float4*)src)[1];
    *(half8*)(Bs + r * SROW + cc) = cvt_h8(f0, f1);
  }

  int wid = tid >> 6, lane = tid & 63;
  int quad = lane >> 4, l16 = lane & 15;
  int mw = wid * 32;                 // wave owns 32 M-rows

  // hoist b_gate (chunk 6 -> cols ni*16+l16, chunk 7 -> cols 64+ni*16+l16)
  float bg0[4], bg1[4];
#pragma unroll
  for (int ni = 0; ni < 4; ni++) {
    bg0[ni] = b_gate[ni * 16 + l16];
    bg1[ni] = b_gate[64 + ni * 16 + l16];
  }

  __syncthreads();                   // A + B0 visible

  for (int c = 0; c < 9; c++) {
    const _Float16* Bcur = Bs + (c & 1) * BSZ;
    _Float16* Bnxt = Bs + ((c + 1) & 1) * BSZ;

    // ---- issue chunk c+1 loads NOW (they fly under MFMA + epilogue) ----
    float4 pf0[4], pf1[4];
    if (c < 8) {
#pragma unroll
      for (int i = 0; i < 4; i++) {
        int u = tid + i * 256;
        int r = u >> 4;
        int cc = (u & 15) * 8;
        int grow = (c + 1) * 64 + r;
        const float* src = nullptr;
        if (grow < 384)      src = Wqkv + (size_t)grow * 128 + cc;
        else if (grow < 512) src = Wgate + (size_t)(grow - 384) * 128 + cc;
        else if (grow < 520) src = wbias + (size_t)(grow - 512) * 128 + cc;
        if (src) { pf0[i] = ((const float4*)src)[0]; pf1[i] = ((const float4*)src)[1]; }
        else { pf0[i] = make_float4(0.f, 0.f, 0.f, 0.f); pf1[i] = pf0[i]; }
      }
      __builtin_amdgcn_sched_barrier(0);  // pin: loads issue before the MFMA region
    }

    // ---- MFMA on current buffer ----
    floatx4 acc[2][4] = {};
#pragma unroll
    for (int kc = 0; kc < 4; kc++) {
      int ko = kc * 32 + quad * 8;
      half8 a0 = *(const half8*)(As + (mw + l16) * SROW + ko);
      half8 a1 = *(const half8*)(As + (mw + 16 + l16) * SROW + ko);
      half8 b[4];
#pragma unroll
      for (int ni = 0; ni < 4; ni++)
        b[ni] = *(const half8*)(Bcur + (ni * 16 + l16) * SROW + ko);
#pragma unroll
      for (int ni = 0; ni < 4; ni++) {
        acc[0][ni] = __builtin_amdgcn_mfma_f32_16x16x32_f16(a0, b[ni], acc[0][ni], 0, 0, 0);
        acc[1][ni] = __builtin_amdgcn_mfma_f32_16x16x32_f16(a1, b[ni], acc[1][ni], 0, 0, 0);
      }
    }

    // ---- epilogue stores for chunk c ----
    if (c == 8) {                    // bias chunk: only cols 512..519 real
      if (l16 < 8) {
#pragma unroll
        for (int mi = 0; mi < 2; mi++)
#pragma unroll
          for (int r = 0; r < 4; r++) {
            int row = m0 + mw + mi * 16 + quad * 4 + r;
            if (row < M) bias[(size_t)row * 8 + l16] = acc[mi][0][r];
          }
      }
    } else {
      int reg = c >> 1;              // 0:Q 1:K 2:V 3:gate (wave-uniform)
#pragma unroll
      for (int mi = 0; mi < 2; mi++) {
#pragma unroll
        for (int ni = 0; ni < 4; ni++) {
          int colL = (c & 1) * 64 + ni * 16 + l16;   // 0..127 within region
          float bgv = (c & 1) ? bg1[ni] : bg0[ni];
#pragma unroll
          for (int r = 0; r < 4; r++) {
            int row = m0 + mw + mi * 16 + quad * 4 + r;
            if (row >= M) continue;
            float v = acc[mi][ni][r];
            if (reg == 0)      Q[(size_t)row * 128 + colL] = (_Float16)v;
            else if (reg == 1) KV[(size_t)row * 256 + colL] = (_Float16)v;
            else if (reg == 2) KV[(size_t)row * 256 + 128 + colL] = (_Float16)v;
            else gate[(size_t)row * 128 + colL] =
                   (_Float16)(1.0f / (1.0f + __expf(-(v + bgv))));
          }
        }
      }
    }

    // ---- write prefetched chunk into the other buffer; ONE barrier per chunk ----
    if (c < 8) {
#pragma unroll
      for (int i = 0; i < 4; i++) {
        int u = tid + i * 256;
        int r = u >> 4;
        int cc = (u & 15) * 8;
        *(half8*)(Bnxt + r * SROW + cc) = cvt_h8(pf0[i], pf1[i]);
      }
      __syncthreads();               // Bnxt visible; also fences next iter's writes
    }
  }
}

// ================= final GEMM: gated16(Mx128) @ Wo^T(128x128,f32->f16 inline) -> out(f32) =====
__global__ __launch_bounds__(256) void final_gemm_mfma(
    const _Float16* __restrict__ A, const float* __restrict__ Wo,
    float* __restrict__ C, int M) {
  __shared__ _Float16 As[128 * SROW];
  __shared__ _Float16 Bs[64 * SROW];
  int tid = threadIdx.x;
  int m0 = blockIdx.x * 128, n0 = blockIdx.y * 64;
#pragma unroll
  for (int i = 0; i < 8; i++) {
    int u = tid + i * 256;
    int r = u >> 4;
    int cc = (u & 15) * 8;
    int gr = m0 + r;
    int4 val = make_int4(0, 0, 0, 0);
    if (gr < M) val = *(const int4*)(A + (size_t)gr * 128 + cc);
    *(int4*)(As + r * SROW + cc) = val;
  }
#pragma unroll
  for (int i = 0; i < 4; i++) {
    int u = tid + i * 256;
    int r = u >> 4;
    int cc = (u & 15) * 8;
    const float* src = Wo + (size_t)(n0 + r) * 128 + cc;
    float4 f0 = ((const float4*)src)[0];
    float4 f1 = ((const float4*)src)[1];
    *(half8*)(Bs + r * SROW + cc) = cvt_h8(f0, f1);
  }
  __syncthreads();

  int wid = tid >> 6, lane = tid & 63;
  int quad = lane >> 4, l16 = lane & 15;
  int mw = (wid >> 1) * 64;
  int nw = (wid & 1) * 32;

  floatx4 acc[4][2] = {};
#pragma unroll
  for (int kc = 0; kc < 4; kc++) {
    int ko = kc * 32 + quad * 8;
    half8 a[4], b[2];
#pragma unroll
    for (int mi = 0; mi < 4; mi++)
      a[mi] = *(const half8*)(As + (mw + mi * 16 + l16) * SROW + ko);
#pragma unroll
    for (int ni = 0; ni < 2; ni++)
      b[ni] = *(const half8*)(Bs + (nw + ni * 16 + l16) * SROW + ko);
#pragma unroll
    for (int mi = 0; mi < 4; mi++)
#pragma unroll
      for (int ni = 0; ni < 2; ni++)
        acc[mi][ni] = __builtin_amdgcn_mfma_f32_16x16x32_f16(a[mi], b[ni], acc[mi][ni], 0, 0, 0);
  }
#pragma unroll
  for (int mi = 0; mi < 4; mi++) {
#pragma unroll
    for (int ni = 0; ni < 2; ni++) {
      int col = n0 + nw + ni * 16 + l16;
#pragma unroll
      for (int r = 0; r < 4; r++) {
        int row = m0 + mw + mi * 16 + quad * 4 + r;
        if (row >= M) continue;
        C[(size_t)row * 128 + col] = acc[mi][ni][r];
      }
    }
  }
}

// ============ fused attention: one wave/node, quarter-wave per edge ========
// R2's measured-58.9us form: depth-4 static-slot pipeline, NT loads on one-shot streams.
// int csr_dst; gated store CACHED (final_gemm re-reads it).
// lane = qtr*16 + l16; lane owns channels [l16*8, l16*8+8); head = l16>>1
__global__ __launch_bounds__(256) void attn_fused(
    const int* __restrict__ cnt, const int* __restrict__ csr_dst,
    const _Float16* __restrict__ Q, const _Float16* __restrict__ KV,
    const float* __restrict__ bias, const _Float16* __restrict__ gate,
    _Float16* __restrict__ gated, int N) {
  int wave = threadIdx.x >> 6, lane = threadIdx.x & 63;
  int n = blockIdx.x * 4 + wave;
  if (n >= N) return;
  int deg = __builtin_nontemporal_load(cnt + n);
  if (deg > MAXDEG) deg = MAXDEG;
  int qtr = lane >> 4, l16 = lane & 15;
  int ch0 = l16 * 8;

  int dstv = __builtin_nontemporal_load(csr_dst + (size_t)n * MAXDEG + lane);

  H8 qu; qu.v = __builtin_nontemporal_load((const half8*)(Q + (size_t)n * DM + ch0));
  float bias_h = __builtin_nontemporal_load(bias + (size_t)n * NHEADS + (l16 >> 1));

  float acc[8] = {};
  float den = 0.f;
  int iters = (deg + 3) >> 2;        // 4 edges per iteration (one per quarter-wave)

  H8 kb[4], vb[4];
  bool bb[4];
#pragma unroll
  for (int j = 0; j < 4; j++) {
    bb[j] = false;
    kb[j].v = half8{}; vb[j].v = half8{};
    if (j < iters) {                 // wave-uniform
      int e = j * 4 + qtr;
      bb[j] = e < deg;
      int d = __shfl(dstv, e);
      d = bb[j] ? d : 0;
      const _Float16* kvp = KV + (size_t)d * 256 + ch0;
      kb[j].v = *(const half8*)kvp;
      vb[j].v = *(const half8*)(kvp + 128);
    }
  }

  for (int base = 0; base < iters; base += 4) {
#pragma unroll
    for (int j = 0; j < 4; j++) {
      float p = 0.f;
#pragma unroll
      for (int t = 0; t < 4; t++)
        p = __builtin_amdgcn_fdot2(qu.h2[t], kb[j].h2[t], p, false);
      p += __shfl_xor(p, 1);
      float w = __expf(p * 0.25f + bias_h);   // scale=1/sqrt(16); scores O(10), fp32-safe
      if (!bb[j]) w = 0.f;
      den += w;
#pragma unroll
      for (int t = 0; t < 8; t++) acc[t] = fmaf(w, (float)vb[j].v[t], acc[t]);
      int idx = base + 4 + j;
      bb[j] = false;
      if (idx < iters) {             // wave-uniform; also guarantees e <= 63 for shfl
        int e = idx * 4 + qtr;
        bb[j] = e < deg;
        int d = __shfl(dstv, e);
        d = bb[j] ? d : 0;
        const _Float16* kvp = KV + (size_t)d * 256 + ch0;
        kb[j].v = *(const half8*)kvp;
        vb[j].v = *(const half8*)(kvp + 128);
      }
    }
  }

#pragma unroll
  for (int j = 0; j < 8; j++) acc[j] += __shfl_xor(acc[j], 16);
#pragma unroll
  for (int j = 0; j < 8; j++) acc[j] += __shfl_xor(acc[j], 32);
  den += __shfl_xor(den, 16);
  den += __shfl_xor(den, 32);

  if (qtr == 0) {
    float inv = 1.0f / (den + 1e-12f);
    half8 gv = __builtin_nontemporal_load((const half8*)(gate + (size_t)n * DM + ch0));
    half8 o;
#pragma unroll
    for (int j = 0; j < 8; j++) o[j] = (_Float16)(acc[j] * inv * (float)gv[j]);
    *(half8*)(gated + (size_t)n * DM + ch0) = o;   // cached: final_gemm re-reads
  }
}

extern "C" void kernel_launch(void* const* d_in, const int* in_sizes, int n_in,
                              void* d_out, int out_size, void* d_ws, size_t ws_size,
                              hipStream_t stream) {
  const float* X     = (const float*)d_in[0];
  const float* Wqkv  = (const float*)d_in[1];
  const float* wbias = (const float*)d_in[2];
  const float* Wgate = (const float*)d_in[3];
  const float* bgate = (const float*)d_in[4];
  const float* Wo    = (const float*)d_in[5];
  const int*   nsrc  = (const int*)d_in[6];
  const int*   ndst  = (const int*)d_in[7];
  int N = in_sizes[0] / 128;
  int E = in_sizes[6];
  float* out = (float*)d_out;

  char* p = (char*)d_ws;
  _Float16* Q16     = (_Float16*)p; p += (size_t)N * 128 * sizeof(_Float16);
  _Float16* KV16    = (_Float16*)p; p += (size_t)N * 256 * sizeof(_Float16);
  _Float16* gate16  = (_Float16*)p; p += (size_t)N * 128 * sizeof(_Float16);
  _Float16* gated16 = (_Float16*)p; p += (size_t)N * 128 * sizeof(_Float16);
  float* bias       = (float*)p;    p += (size_t)N * 8 * sizeof(float);
  int* cnt          = (int*)p;      p += (size_t)N * sizeof(int);
  int* csr_dst      = (int*)p;      p += (size_t)N * MAXDEG * sizeof(int);

  hipMemsetAsync(cnt, 0, (size_t)N * sizeof(int), stream);

  int P = (N + 127) / 128;                 // proj blocks
  int C = (E + 8191) / 8192;               // csr blocks (grid FRONT)
  proj_csr<<<C + P, 256, 0, stream>>>(X, Wqkv, Wgate, wbias, bgate, nsrc, ndst,
                                      cnt, csr_dst, Q16, KV16, gate16, bias, N, E, C);

  attn_fused<<<(N + 3) / 4, 256, 0, stream>>>(cnt, csr_dst, Q16, KV16, bias,
                                              gate16, gated16, N);

  dim3 fg((N + 127) / 128, 2);
  final_gemm_mfma<<<fg, 256, 0, stream>>>(gated16, Wo, out, N);
}

// Round 9
// 217.168 us; speedup vs baseline: 1.0469x; 1.0469x over previous
//
#include <hip/hip_runtime.h>
#include <hip/hip_fp16.h>

#define DM 128
#define NHEADS 8
#define MAXDEG 64
#define SROW 136    // LDS row stride in halves: 128+8 pad (2-way bank alias = free)
#define FSTRIDE 132 // Wo LDS row stride in halves: 264B rows -> banks 2r..2r+3, 2-way max

typedef _Float16 half8 __attribute__((ext_vector_type(8)));
typedef _Float16 half2v __attribute__((ext_vector_type(2)));
typedef float floatx4 __attribute__((ext_vector_type(4)));

union H8 { half8 v; half2v h2[4]; };

__device__ __forceinline__ half8 cvt_h8(float4 f0, float4 f1) {
  return half8{(_Float16)f0.x, (_Float16)f0.y, (_Float16)f0.z, (_Float16)f0.w,
               (_Float16)f1.x, (_Float16)f1.y, (_Float16)f1.z, (_Float16)f1.w};
}

// ================= fused: proj GEMM blocks [0,P) + CSR-build blocks [P,P+C) =================
// FROZEN at R7 form (best measured: 66-71us). 8 structural experiments (barrier removal,
// dbuf, occupancy doubling, NT stores, reg-resident B) all landed 66-129us -> this is the
// best found; the kernel is latency-bound under full-machine contention in a way staging
// micro-structure does not fix.
// chunk pairs: 0,1->Q  2,3->K(KV lo)  4,5->V(KV hi)  6,7->gate  8->bias cols 512..519
__global__ __launch_bounds__(256) void proj_csr(
    const float* __restrict__ X, const float* __restrict__ Wqkv,
    const float* __restrict__ Wgate, const float* __restrict__ wbias,
    const float* __restrict__ b_gate,
    const int* __restrict__ nsrc, const int* __restrict__ ndst,
    int* __restrict__ cnt, int* __restrict__ csr_dst,
    _Float16* __restrict__ Q, _Float16* __restrict__ KV,
    _Float16* __restrict__ gate, float* __restrict__ bias,
    int M, int E, int P) {
  __shared__ _Float16 As[128 * SROW];
  __shared__ _Float16 Bs[64 * SROW];
  int tid = threadIdx.x;
  int bid = blockIdx.x;

  if (bid >= P) {
    // ---------------- CSR build role ----------------
    int ebase = (bid - P) * 8192;
    for (int g = 0; g < 4; g++) {
      int s[8], d[8];
#pragma unroll
      for (int j = 0; j < 8; j++) {
        int e = ebase + (g * 8 + j) * 256 + tid;
        s[j] = (e < E) ? nsrc[e] : -1;
        d[j] = (e < E) ? ndst[e] : 0;
      }
#pragma unroll
      for (int j = 0; j < 8; j++) {
        if (s[j] >= 0) {
          int p = atomicAdd(&cnt[s[j]], 1);
          if (p < MAXDEG) csr_dst[(size_t)s[j] * MAXDEG + p] = d[j];
        }
      }
    }
    return;
  }

  // ---------------- projection GEMM role ----------------
  int m0 = bid * 128;

  // stage A (fp32 -> fp16): 128 rows x 128 cols
#pragma unroll
  for (int i = 0; i < 4; i++) {
    int u = tid + i * 256;           // 0..1023
    int r = u >> 3;
    int cc = (u & 7) * 16;
    int gr = m0 + r;
    float4 f0, f1, f2, f3;
    if (gr < M) {
      const float4* src = (const float4*)(X + (size_t)gr * 128 + cc);
      f0 = src[0]; f1 = src[1]; f2 = src[2]; f3 = src[3];
    } else {
      f0 = f1 = f2 = f3 = make_float4(0.f, 0.f, 0.f, 0.f);
    }
    *(half8*)(As + r * SROW + cc) = cvt_h8(f0, f1);
    *(half8*)(As + r * SROW + cc + 8) = cvt_h8(f2, f3);
  }

  int wid = tid >> 6, lane = tid & 63;
  int quad = lane >> 4, l16 = lane & 15;
  int mw = wid * 32;                 // wave owns 32 M-rows

  // hoist b_gate (chunk 6 -> cols ni*16+l16, chunk 7 -> cols 64+ni*16+l16)
  float bg0[4], bg1[4];
#pragma unroll
  for (int ni = 0; ni < 4; ni++) {
    bg0[ni] = b_gate[ni * 16 + l16];
    bg1[ni] = b_gate[64 + ni * 16 + l16];
  }

  for (int c = 0; c < 9; c++) {
    __syncthreads();                 // previous chunk's Bs readers done (orders A on c=0)
    // stage B chunk c with inline f32->f16 conversion
#pragma unroll
    for (int i = 0; i < 4; i++) {
      int u = tid + i * 256;         // 0..1023
      int r = u >> 4;                // 0..63
      int cc = (u & 15) * 8;
      int grow = c * 64 + r;
      const float* src = nullptr;
      if (grow < 384)      src = Wqkv + (size_t)grow * 128 + cc;
      else if (grow < 512) src = Wgate + (size_t)(grow - 384) * 128 + cc;
      else if (grow < 520) src = wbias + (size_t)(grow - 512) * 128 + cc;
      half8 h = {};
      if (src) {
        float4 f0 = ((const float4*)src)[0];
        float4 f1 = ((const float4*)src)[1];
        h = cvt_h8(f0, f1);
      }
      *(half8*)(Bs + r * SROW + cc) = h;
    }
    __syncthreads();

    floatx4 acc[2][4] = {};
#pragma unroll
    for (int kc = 0; kc < 4; kc++) {
      int ko = kc * 32 + quad * 8;
      half8 a0 = *(const half8*)(As + (mw + l16) * SROW + ko);
      half8 a1 = *(const half8*)(As + (mw + 16 + l16) * SROW + ko);
      half8 b[4];
#pragma unroll
      for (int ni = 0; ni < 4; ni++)
        b[ni] = *(const half8*)(Bs + (ni * 16 + l16) * SROW + ko);
#pragma unroll
      for (int ni = 0; ni < 4; ni++) {
        acc[0][ni] = __builtin_amdgcn_mfma_f32_16x16x32_f16(a0, b[ni], acc[0][ni], 0, 0, 0);
        acc[1][ni] = __builtin_amdgcn_mfma_f32_16x16x32_f16(a1, b[ni], acc[1][ni], 0, 0, 0);
      }
    }

    if (c == 8) {                    // bias chunk: only cols 512..519 real
      if (l16 < 8) {
#pragma unroll
        for (int mi = 0; mi < 2; mi++)
#pragma unroll
          for (int r = 0; r < 4; r++) {
            int row = m0 + mw + mi * 16 + quad * 4 + r;
            if (row < M) bias[(size_t)row * 8 + l16] = acc[mi][0][r];
          }
      }
    } else {
      int reg = c >> 1;              // 0:Q 1:K 2:V 3:gate (wave-uniform)
#pragma unroll
      for (int mi = 0; mi < 2; mi++) {
#pragma unroll
        for (int ni = 0; ni < 4; ni++) {
          int colL = (c & 1) * 64 + ni * 16 + l16;   // 0..127 within region
          float bgv = (c & 1) ? bg1[ni] : bg0[ni];
#pragma unroll
          for (int r = 0; r < 4; r++) {
            int row = m0 + mw + mi * 16 + quad * 4 + r;
            if (row >= M) continue;
            float v = acc[mi][ni][r];
            if (reg == 0)      Q[(size_t)row * 128 + colL] = (_Float16)v;
            else if (reg == 1) KV[(size_t)row * 256 + colL] = (_Float16)v;
            else if (reg == 2) KV[(size_t)row * 256 + 128 + colL] = (_Float16)v;
            else gate[(size_t)row * 128 + colL] =
                   (_Float16)(1.0f / (1.0f + __expf(-(v + bgv))));
          }
        }
      }
    }
  }
}

// ======= final GEMM rewrite: Wo staged once, ONE barrier, grid-stride streaming waves ======
// Old form (128-row block, LDS-stage A+B per block, barrier) was structurally identical to
// one proj chunk -> suspected of sharing proj's latency disease (never profiled: always
// below top-5 cutoff). New form: after the single Wo-stage barrier, each wave independently
// streams 16-row tiles: 4 coalesced 16B A-loads -> 32 MFMA (B from LDS, 2-way conflict max)
// -> 32 stores. No inter-iteration dependencies, no further barriers.
__global__ __launch_bounds__(256) void final_gemm_reg(
    const _Float16* __restrict__ A, const float* __restrict__ Wo,
    float* __restrict__ C, int M) {
  __shared__ _Float16 Ws[128 * FSTRIDE];   // 33 KB -> LDS allows 4 blocks/CU
  int tid = threadIdx.x;
  // stage Wo (f32 -> f16): 128 x 128, coalesced 32B per thread-slot
#pragma unroll
  for (int i = 0; i < 8; i++) {
    int u = tid + i * 256;           // 0..2047
    int r = u >> 4;                  // 0..127
    int cc = (u & 15) * 8;
    const float* src = Wo + (size_t)r * 128 + cc;
    float4 f0 = ((const float4*)src)[0];
    float4 f1 = ((const float4*)src)[1];
    *(half8*)(Ws + r * FSTRIDE + cc) = cvt_h8(f0, f1);
  }
  __syncthreads();                   // the only barrier

  int wid = tid >> 6, lane = tid & 63;
  int quad = lane >> 4, l16 = lane & 15;
  int tiles = (M + 15) >> 4;
  int gw = blockIdx.x * 4 + wid;     // global wave id
  int nw = gridDim.x * 4;            // total waves

  for (int t = gw; t < tiles; t += nw) {
    int r0 = t * 16;
    int arow = r0 + l16;
    half8 af[4];
#pragma unroll
    for (int kc = 0; kc < 4; kc++)
      af[kc] = (arow < M) ? *(const half8*)(A + (size_t)arow * 128 + kc * 32 + quad * 8)
                          : half8{};
    floatx4 acc[8] = {};
#pragma unroll
    for (int kc = 0; kc < 4; kc++) {
      int ko = kc * 32 + quad * 8;
#pragma unroll
      for (int ni = 0; ni < 8; ni++) {
        half8 bf = *(const half8*)(Ws + (ni * 16 + l16) * FSTRIDE + ko);
        acc[ni] = __builtin_amdgcn_mfma_f32_16x16x32_f16(af[kc], bf, acc[ni], 0, 0, 0);
      }
    }
#pragma unroll
    for (int ni = 0; ni < 8; ni++) {
      int col = ni * 16 + l16;
#pragma unroll
      for (int r = 0; r < 4; r++) {
        int row = r0 + quad * 4 + r;
        if (row < M) C[(size_t)row * 128 + col] = acc[ni][r];
      }
    }
  }
}

// ============ fused attention: one wave/node, quarter-wave per edge ========
// R2's measured-58.9us form (unchanged): depth-4 static-slot pipeline, NT loads on
// one-shot streams, int csr_dst, cached gated store.
// lane = qtr*16 + l16; lane owns channels [l16*8, l16*8+8); head = l16>>1
__global__ __launch_bounds__(256) void attn_fused(
    const int* __restrict__ cnt, const int* __restrict__ csr_dst,
    const _Float16* __restrict__ Q, const _Float16* __restrict__ KV,
    const float* __restrict__ bias, const _Float16* __restrict__ gate,
    _Float16* __restrict__ gated, int N) {
  int wave = threadIdx.x >> 6, lane = threadIdx.x & 63;
  int n = blockIdx.x * 4 + wave;
  if (n >= N) return;
  int deg = __builtin_nontemporal_load(cnt + n);
  if (deg > MAXDEG) deg = MAXDEG;
  int qtr = lane >> 4, l16 = lane & 15;
  int ch0 = l16 * 8;

  int dstv = __builtin_nontemporal_load(csr_dst + (size_t)n * MAXDEG + lane);

  H8 qu; qu.v = __builtin_nontemporal_load((const half8*)(Q + (size_t)n * DM + ch0));
  float bias_h = __builtin_nontemporal_load(bias + (size_t)n * NHEADS + (l16 >> 1));

  float acc[8] = {};
  float den = 0.f;
  int iters = (deg + 3) >> 2;        // 4 edges per iteration (one per quarter-wave)

  H8 kb[4], vb[4];
  bool bb[4];
#pragma unroll
  for (int j = 0; j < 4; j++) {
    bb[j] = false;
    kb[j].v = half8{}; vb[j].v = half8{};
    if (j < iters) {                 // wave-uniform
      int e = j * 4 + qtr;
      bb[j] = e < deg;
      int d = __shfl(dstv, e);
      d = bb[j] ? d : 0;
      const _Float16* kvp = KV + (size_t)d * 256 + ch0;
      kb[j].v = *(const half8*)kvp;
      vb[j].v = *(const half8*)(kvp + 128);
    }
  }

  for (int base = 0; base < iters; base += 4) {
#pragma unroll
    for (int j = 0; j < 4; j++) {
      float p = 0.f;
#pragma unroll
      for (int t = 0; t < 4; t++)
        p = __builtin_amdgcn_fdot2(qu.h2[t], kb[j].h2[t], p, false);
      p += __shfl_xor(p, 1);
      float w = __expf(p * 0.25f + bias_h);   // scale=1/sqrt(16); scores O(10), fp32-safe
      if (!bb[j]) w = 0.f;
      den += w;
#pragma unroll
      for (int t = 0; t < 8; t++) acc[t] = fmaf(w, (float)vb[j].v[t], acc[t]);
      int idx = base + 4 + j;
      bb[j] = false;
      if (idx < iters) {             // wave-uniform; also guarantees e <= 63 for shfl
        int e = idx * 4 + qtr;
        bb[j] = e < deg;
        int d = __shfl(dstv, e);
        d = bb[j] ? d : 0;
        const _Float16* kvp = KV + (size_t)d * 256 + ch0;
        kb[j].v = *(const half8*)kvp;
        vb[j].v = *(const half8*)(kvp + 128);
      }
    }
  }

#pragma unroll
  for (int j = 0; j < 8; j++) acc[j] += __shfl_xor(acc[j], 16);
#pragma unroll
  for (int j = 0; j < 8; j++) acc[j] += __shfl_xor(acc[j], 32);
  den += __shfl_xor(den, 16);
  den += __shfl_xor(den, 32);

  if (qtr == 0) {
    float inv = 1.0f / (den + 1e-12f);
    half8 gv = __builtin_nontemporal_load((const half8*)(gate + (size_t)n * DM + ch0));
    half8 o;
#pragma unroll
    for (int j = 0; j < 8; j++) o[j] = (_Float16)(acc[j] * inv * (float)gv[j]);
    *(half8*)(gated + (size_t)n * DM + ch0) = o;   // cached: final_gemm re-reads
  }
}

extern "C" void kernel_launch(void* const* d_in, const int* in_sizes, int n_in,
                              void* d_out, int out_size, void* d_ws, size_t ws_size,
                              hipStream_t stream) {
  const float* X     = (const float*)d_in[0];
  const float* Wqkv  = (const float*)d_in[1];
  const float* wbias = (const float*)d_in[2];
  const float* Wgate = (const float*)d_in[3];
  const float* bgate = (const float*)d_in[4];
  const float* Wo    = (const float*)d_in[5];
  const int*   nsrc  = (const int*)d_in[6];
  const int*   ndst  = (const int*)d_in[7];
  int N = in_sizes[0] / 128;
  int E = in_sizes[6];
  float* out = (float*)d_out;

  char* p = (char*)d_ws;
  _Float16* Q16     = (_Float16*)p; p += (size_t)N * 128 * sizeof(_Float16);
  _Float16* KV16    = (_Float16*)p; p += (size_t)N * 256 * sizeof(_Float16);
  _Float16* gate16  = (_Float16*)p; p += (size_t)N * 128 * sizeof(_Float16);
  _Float16* gated16 = (_Float16*)p; p += (size_t)N * 128 * sizeof(_Float16);
  float* bias       = (float*)p;    p += (size_t)N * 8 * sizeof(float);
  int* cnt          = (int*)p;      p += (size_t)N * sizeof(int);
  int* csr_dst      = (int*)p;      p += (size_t)N * MAXDEG * sizeof(int);

  hipMemsetAsync(cnt, 0, (size_t)N * sizeof(int), stream);

  int P = (N + 127) / 128;                 // proj blocks
  int C = (E + 8191) / 8192;               // csr blocks (last in grid, R7-exact)
  proj_csr<<<P + C, 256, 0, stream>>>(X, Wqkv, Wgate, wbias, bgate, nsrc, ndst,
                                      cnt, csr_dst, Q16, KV16, gate16, bias, N, E, P);

  attn_fused<<<(N + 3) / 4, 256, 0, stream>>>(cnt, csr_dst, Q16, KV16, bias,
                                              gate16, gated16, N);

  // grid-stride: 512 blocks = 2048 waves over (M+15)/16 = ~3125 tiles
  final_gemm_reg<<<512, 256, 0, stream>>>(gated16, Wo, out, N);
}